// Round 9
// baseline (367.996 us; speedup 1.0000x reference)
//
#include <hip/hip_runtime.h>
#include <math.h>

#define NN 50000
#define NE 800000
#define D  128

// ---- fused prep: h->bf16 pack + in-degree/rank atomics + out-tail zero ----
// grid 12500 x 256 = 3.2M threads = NN*64 cvt items; first NE do edge work;
// first tailN zero the int-tail of d_out.
__global__ __launch_bounds__(256) void k_pre(const float* __restrict__ h,
                                             unsigned* __restrict__ hb,
                                             const int* __restrict__ ei,
                                             int* __restrict__ deg,
                                             unsigned short* __restrict__ rank,
                                             int* __restrict__ outtail, int tailN) {
    int t = blockIdx.x * 256 + threadIdx.x;
    float2 v = ((const float2*)h)[t];
    unsigned a = __float_as_uint(v.x);
    unsigned b = __float_as_uint(v.y);
    a = a + 0x7FFFu + ((a >> 16) & 1u);           // RNE to bf16
    b = b + 0x7FFFu + ((b >> 16) & 1u);
    hb[t] = (a >> 16) | (b & 0xFFFF0000u);
    if (t < NE) {
        int dst = ei[NE + t];
        rank[t] = (unsigned short)atomicAdd(&deg[dst], 1);
    }
    if (t < tailN) outtail[t] = 0;
}

// ---- single-block scan: rowoff (exclusive) + dinv, no inter-block sync ----
// 1024 threads, 49 elements each (49*1024 >= NN). Two-pass per thread.
__global__ __launch_bounds__(1024) void k_scan(const int* __restrict__ deg,
                                               int* __restrict__ rowoff,
                                               float* __restrict__ dinv) {
    __shared__ int sb[1024];
    int t = threadIdx.x;
    int base = t * 49;
    int s = 0;
    for (int j = 0; j < 49; j++) {
        int i = base + j;
        if (i < NN) s += deg[i];
    }
    sb[t] = s; __syncthreads();
    // Hillis-Steele inclusive scan over 1024
    for (int off = 1; off < 1024; off <<= 1) {
        int v = (t >= off) ? sb[t - off] : 0;
        __syncthreads();
        sb[t] += v;
        __syncthreads();
    }
    int ex = sb[t] - s;   // exclusive prefix for this thread's chunk
    for (int j = 0; j < 49; j++) {
        int i = base + j;
        if (i < NN) {
            int d = deg[i];
            rowoff[i] = ex;
            dinv[i] = rsqrtf((float)d + 1.0f);   // +1 self loop
            ex += d;
            if (i == NN - 1) rowoff[NN] = ex;    // sentinel = NE
        }
    }
}

// ---------------- CSR fill: NO atomics (uses precomputed rank) ----------------
__global__ __launch_bounds__(320) void k_fill(const int* __restrict__ ei,
                                              const int* __restrict__ rowoff,
                                              const unsigned short* __restrict__ rank,
                                              int* __restrict__ csr) {
    int t = blockIdx.x * 320 + threadIdx.x;   // 625 blocks * 320 * 4 = NE
    int4 s4 = ((const int4*)ei)[t];
    int4 d4 = ((const int4*)(ei + NE))[t];
    ushort4 r4 = ((const ushort4*)rank)[t];
    csr[rowoff[d4.x] + r4.x] = s4.x;
    csr[rowoff[d4.y] + r4.y] = s4.y;
    csr[rowoff[d4.z] + r4.z] = s4.z;
    csr[rowoff[d4.w] + r4.w] = s4.w;
}

// ---------------- fused: gather(bf16) + GEMM(fp32) + bias + LN + tanh --------
// R6 structure (256 thr, 4 indep waves, 4 rows/wave, NO LDS, VGPR~40-56).
// Edge loop unrolled x8 for MLP (R8: 4-deep left latency on the table).
// GEMM unroll capped at 4 (full unroll spills: R4 postmortem).
__global__ __launch_bounds__(256) void k_main(
        const int* __restrict__ rowoff, const int* __restrict__ csr,
        const float* __restrict__ dinv, const float* __restrict__ h,
        const unsigned* __restrict__ hb,
        const float* __restrict__ Wg,   const float* __restrict__ bias,
        const float* __restrict__ gamma,const float* __restrict__ beta,
        float* __restrict__ out) {
    int tid = threadIdx.x;
    int w = tid >> 6, lane = tid & 63;
    int rowBase = blockIdx.x * 16 + w * 4;
    const float2* h2 = (const float2*)h;
    const float2* W2 = (const float2*)Wg;

    // ---- gather into registers: x[r] = dn*(dn*h[row] + sum dinv[s]*hb[s]) ----
    float2 x[4];
    for (int r = 0; r < 4; r++) {
        int row = rowBase + r;
        float dn = dinv[row];
        float2 hv = h2[(size_t)row * 64 + lane];   // self-loop in fp32
        float2 a;
        a.x = dn * hv.x; a.y = dn * hv.y;
        int start = rowoff[row], end = rowoff[row + 1];
        for (int c = start; c < end; c += 64) {
            int m = end - c; if (m > 64) m = 64;
            int s = 0; float wv = 0.f;
            if (lane < m) { s = csr[c + lane]; wv = dinv[s]; }
            int j = 0;
            for (; j + 7 < m; j += 8) {          // 8 loads in flight
                unsigned p[8]; float wj[8];
#pragma unroll
                for (int q = 0; q < 8; q++) {
                    int sq = __shfl(s, j + q, 64);
                    wj[q]  = __shfl(wv, j + q, 64);
                    p[q]   = hb[(size_t)sq * 64 + lane];
                }
#pragma unroll
                for (int q = 0; q < 8; q++) {
                    a.x = fmaf(wj[q], __uint_as_float(p[q] << 16), a.x);
                    a.y = fmaf(wj[q], __uint_as_float(p[q] & 0xFFFF0000u), a.y);
                }
            }
            for (; j < m; j++) {
                int   sj = __shfl(s,  j, 64);
                float fj = __shfl(wv, j, 64);
                unsigned pj = hb[(size_t)sj * 64 + lane];
                a.x = fmaf(fj, __uint_as_float(pj << 16), a.x);
                a.y = fmaf(fj, __uint_as_float(pj & 0xFFFF0000u), a.y);
            }
        }
        a.x *= dn; a.y *= dn;
        x[r] = a;
    }

    // ---- GEMM via register broadcast: y[c] = sum_k x[k] * W[k][c] ----
    float2 acc[4];
#pragma unroll
    for (int r = 0; r < 4; r++) acc[r] = make_float2(0.f, 0.f);

#pragma unroll 4
    for (int j = 0; j < 64; j++) {            // even k = 2j (lane j's .x)
        float2 wv = W2[(size_t)(2 * j) * 64 + lane];
#pragma unroll
        for (int r = 0; r < 4; r++) {
            float xk = __shfl(x[r].x, j, 64);
            acc[r].x = fmaf(xk, wv.x, acc[r].x);
            acc[r].y = fmaf(xk, wv.y, acc[r].y);
        }
    }
#pragma unroll 4
    for (int j = 0; j < 64; j++) {            // odd k = 2j+1 (lane j's .y)
        float2 wv = W2[(size_t)(2 * j + 1) * 64 + lane];
#pragma unroll
        for (int r = 0; r < 4; r++) {
            float xk = __shfl(x[r].y, j, 64);
            acc[r].x = fmaf(xk, wv.x, acc[r].x);
            acc[r].y = fmaf(xk, wv.y, acc[r].y);
        }
    }

    // ---- bias + LN + tanh + store ----
    float2 bi = ((const float2*)bias)[lane];
    float2 ga = ((const float2*)gamma)[lane];
    float2 be = ((const float2*)beta)[lane];
#pragma unroll
    for (int r = 0; r < 4; r++) {
        int row = rowBase + r;
        float y0 = acc[r].x + bi.x;
        float y1 = acc[r].y + bi.y;
        float s = y0 + y1;
#pragma unroll
        for (int off = 32; off > 0; off >>= 1) s += __shfl_xor(s, off, 64);
        float m = s * (1.0f / 128.0f);
        float v0 = y0 - m, v1 = y1 - m;
        float vs = v0 * v0 + v1 * v1;
#pragma unroll
        for (int off = 32; off > 0; off >>= 1) vs += __shfl_xor(vs, off, 64);
        float rstd = rsqrtf(vs * (1.0f / 128.0f) + 1e-5f);
        float2 o;
        o.x = tanhf(v0 * rstd * ga.x + be.x);
        o.y = tanhf(v1 * rstd * ga.y + be.y);
        *(float2*)&out[(size_t)row * D + lane * 2] = o;
    }
}

extern "C" void kernel_launch(void* const* d_in, const int* in_sizes, int n_in,
                              void* d_out, int out_size, void* d_ws, size_t ws_size,
                              hipStream_t stream) {
    // inputs: t, h, edge_index, batch_size, W, b, gamma, beta
    const float* h     = (const float*)d_in[1];
    const int*   ei    = (const int*)  d_in[2];
    const float* Wg    = (const float*)d_in[4];
    const float* b     = (const float*)d_in[5];
    const float* gamma = (const float*)d_in[6];
    const float* beta  = (const float*)d_in[7];
    float* out = (float*)d_out;

    // workspace layout
    int*            deg    = (int*)d_ws;                      // NN ints
    unsigned short* rank   = (unsigned short*)(deg + NN);     // NE ushorts
    int*            rowoff = (int*)(rank + NE);               // NN+1 ints
    float*          dinv   = (float*)(rowoff + NN + 1);       // NN floats
    int*            csr    = (int*)(dinv + NN);               // NE ints
    unsigned*       hb     = (unsigned*)(csr + NE);           // NN*64 uints (12.8MB)

    int tailN = out_size - NN * D;                 // int-zeros tail of d_out
    int* outtail = (int*)(out + (size_t)NN * D);

    hipMemsetAsync(deg, 0, NN * sizeof(int), stream);
    k_pre  <<<12500, 256, 0, stream>>>(h, hb, ei, deg, rank, outtail, tailN);
    k_scan <<<1,    1024, 0, stream>>>(deg, rowoff, dinv);
    k_fill <<<625,   320, 0, stream>>>(ei, rowoff, rank, csr);
    k_main <<<NN / 16, 256, 0, stream>>>(rowoff, csr, dinv, h, hb, Wg, b, gamma, beta, out);
}

// Round 10
// 258.481 us; speedup vs baseline: 1.4237x; 1.4237x over previous
//
#include <hip/hip_runtime.h>
#include <math.h>

#define NN 50000
#define NE 800000
#define D  128
#define SCAN_CHUNK 1024
#define NSCAN ((NN + SCAN_CHUNK - 1) / SCAN_CHUNK)   // 49

// ---- fused prep: h->bf16 pack + in-degree/rank atomics + out-tail zero ----
__global__ __launch_bounds__(256) void k_pre(const float* __restrict__ h,
                                             unsigned* __restrict__ hb,
                                             const int* __restrict__ ei,
                                             int* __restrict__ deg,
                                             unsigned short* __restrict__ rank,
                                             int* __restrict__ outtail, int tailN) {
    int t = blockIdx.x * 256 + threadIdx.x;   // grid 12500 -> NN*64 cvt items
    float2 v = ((const float2*)h)[t];
    unsigned a = __float_as_uint(v.x);
    unsigned b = __float_as_uint(v.y);
    a = a + 0x7FFFu + ((a >> 16) & 1u);           // RNE to bf16
    b = b + 0x7FFFu + ((b >> 16) & 1u);
    hb[t] = (a >> 16) | (b & 0xFFFF0000u);
    if (t < NE) {
        int dst = ei[NE + t];
        rank[t] = (unsigned short)atomicAdd(&deg[dst], 1);
    }
    if (t < tailN) outtail[t] = 0;
}

// ---------------- scan stage A: per-chunk sums + dinv (49 blocks) ----------
__global__ __launch_bounds__(256) void k_scan_a(const int* __restrict__ deg,
                                                int* __restrict__ partial,
                                                float* __restrict__ dinv) {
    __shared__ int red[256];
    int t = threadIdx.x;
    int base = blockIdx.x * SCAN_CHUNK + t * 4;
    int s = 0;
#pragma unroll
    for (int j = 0; j < 4; j++) {
        int i = base + j;
        if (i < NN) {
            int d = deg[i];
            s += d;
            dinv[i] = rsqrtf((float)d + 1.0f);   // +1 self loop
        }
    }
    red[t] = s; __syncthreads();
#pragma unroll
    for (int off = 128; off > 0; off >>= 1) {
        if (t < off) red[t] += red[t + off];
        __syncthreads();
    }
    if (t == 0) partial[blockIdx.x] = red[0];
}

// ------- scan stage C: wave-prefix of 49 partials + chunk-local scan -------
__global__ __launch_bounds__(256) void k_scan_c(const int* __restrict__ deg,
                                                const int* __restrict__ partial,
                                                int* __restrict__ rowoff) {
    __shared__ int sbuf[256];
    int t = threadIdx.x;
    int lane = t & 63;
    int pv = (lane < NSCAN && lane < (int)blockIdx.x) ? partial[lane] : 0;
#pragma unroll
    for (int off = 32; off > 0; off >>= 1) pv += __shfl_xor(pv, off, 64);

    int base = blockIdx.x * SCAN_CHUNK + t * 4;
    int d[4]; int s = 0;
#pragma unroll
    for (int j = 0; j < 4; j++) {
        d[j] = (base + j < NN) ? deg[base + j] : 0;
        s += d[j];
    }
    sbuf[t] = s; __syncthreads();
    for (int off = 1; off < 256; off <<= 1) {
        int v = (t >= off) ? sbuf[t - off] : 0;
        __syncthreads();
        sbuf[t] += v;
        __syncthreads();
    }
    int ex = sbuf[t] - s + pv;
#pragma unroll
    for (int j = 0; j < 4; j++) {
        int i = base + j;
        if (i < NN) {
            rowoff[i] = ex;
            ex += d[j];
            if (i == NN - 1) rowoff[NN] = ex;   // sentinel = NE
        }
    }
}

// ---------------- CSR fill: NO atomics (uses precomputed rank) ----------------
__global__ __launch_bounds__(320) void k_fill(const int* __restrict__ ei,
                                              const int* __restrict__ rowoff,
                                              const unsigned short* __restrict__ rank,
                                              int* __restrict__ csr) {
    int t = blockIdx.x * 320 + threadIdx.x;   // 625 blocks * 320 * 4 = NE
    int4 s4 = ((const int4*)ei)[t];
    int4 d4 = ((const int4*)(ei + NE))[t];
    ushort4 r4 = ((const ushort4*)rank)[t];
    csr[rowoff[d4.x] + r4.x] = s4.x;
    csr[rowoff[d4.y] + r4.y] = s4.y;
    csr[rowoff[d4.z] + r4.z] = s4.z;
    csr[rowoff[d4.w] + r4.w] = s4.w;
}

// ---------------- fused: gather(bf16) + GEMM(fp32) + bias + LN + tanh --------
// 256 thr = 4 indep waves, 4 rows/wave, NO LDS. Edge loop unrolled x8 (MLP).
// GEMM unroll capped at 4 (full unroll spills: R4 postmortem).
__global__ __launch_bounds__(256) void k_main(
        const int* __restrict__ rowoff, const int* __restrict__ csr,
        const float* __restrict__ dinv, const float* __restrict__ h,
        const unsigned* __restrict__ hb,
        const float* __restrict__ Wg,   const float* __restrict__ bias,
        const float* __restrict__ gamma,const float* __restrict__ beta,
        float* __restrict__ out) {
    int tid = threadIdx.x;
    int w = tid >> 6, lane = tid & 63;
    int rowBase = blockIdx.x * 16 + w * 4;
    const float2* h2 = (const float2*)h;
    const float2* W2 = (const float2*)Wg;

    // ---- gather into registers: x[r] = dn*(dn*h[row] + sum dinv[s]*hb[s]) ----
    float2 x[4];
    for (int r = 0; r < 4; r++) {
        int row = rowBase + r;
        float dn = dinv[row];
        float2 hv = h2[(size_t)row * 64 + lane];   // self-loop in fp32
        float2 a;
        a.x = dn * hv.x; a.y = dn * hv.y;
        int start = rowoff[row], end = rowoff[row + 1];
        for (int c = start; c < end; c += 64) {
            int m = end - c; if (m > 64) m = 64;
            int s = 0; float wv = 0.f;
            if (lane < m) { s = csr[c + lane]; wv = dinv[s]; }
            int j = 0;
            for (; j + 7 < m; j += 8) {          // 8 loads in flight
                unsigned p[8]; float wj[8];
#pragma unroll
                for (int q = 0; q < 8; q++) {
                    int sq = __shfl(s, j + q, 64);
                    wj[q]  = __shfl(wv, j + q, 64);
                    p[q]   = hb[(size_t)sq * 64 + lane];
                }
#pragma unroll
                for (int q = 0; q < 8; q++) {
                    a.x = fmaf(wj[q], __uint_as_float(p[q] << 16), a.x);
                    a.y = fmaf(wj[q], __uint_as_float(p[q] & 0xFFFF0000u), a.y);
                }
            }
            for (; j < m; j++) {
                int   sj = __shfl(s,  j, 64);
                float fj = __shfl(wv, j, 64);
                unsigned pj = hb[(size_t)sj * 64 + lane];
                a.x = fmaf(fj, __uint_as_float(pj << 16), a.x);
                a.y = fmaf(fj, __uint_as_float(pj & 0xFFFF0000u), a.y);
            }
        }
        a.x *= dn; a.y *= dn;
        x[r] = a;
    }

    // ---- GEMM via register broadcast: y[c] = sum_k x[k] * W[k][c] ----
    float2 acc[4];
#pragma unroll
    for (int r = 0; r < 4; r++) acc[r] = make_float2(0.f, 0.f);

#pragma unroll 4
    for (int j = 0; j < 64; j++) {            // even k = 2j (lane j's .x)
        float2 wv = W2[(size_t)(2 * j) * 64 + lane];
#pragma unroll
        for (int r = 0; r < 4; r++) {
            float xk = __shfl(x[r].x, j, 64);
            acc[r].x = fmaf(xk, wv.x, acc[r].x);
            acc[r].y = fmaf(xk, wv.y, acc[r].y);
        }
    }
#pragma unroll 4
    for (int j = 0; j < 64; j++) {            // odd k = 2j+1 (lane j's .y)
        float2 wv = W2[(size_t)(2 * j + 1) * 64 + lane];
#pragma unroll
        for (int r = 0; r < 4; r++) {
            float xk = __shfl(x[r].y, j, 64);
            acc[r].x = fmaf(xk, wv.x, acc[r].x);
            acc[r].y = fmaf(xk, wv.y, acc[r].y);
        }
    }

    // ---- bias + LN + tanh + store ----
    float2 bi = ((const float2*)bias)[lane];
    float2 ga = ((const float2*)gamma)[lane];
    float2 be = ((const float2*)beta)[lane];
#pragma unroll
    for (int r = 0; r < 4; r++) {
        int row = rowBase + r;
        float y0 = acc[r].x + bi.x;
        float y1 = acc[r].y + bi.y;
        float s = y0 + y1;
#pragma unroll
        for (int off = 32; off > 0; off >>= 1) s += __shfl_xor(s, off, 64);
        float m = s * (1.0f / 128.0f);
        float v0 = y0 - m, v1 = y1 - m;
        float vs = v0 * v0 + v1 * v1;
#pragma unroll
        for (int off = 32; off > 0; off >>= 1) vs += __shfl_xor(vs, off, 64);
        float rstd = rsqrtf(vs * (1.0f / 128.0f) + 1e-5f);
        float2 o;
        o.x = tanhf(v0 * rstd * ga.x + be.x);
        o.y = tanhf(v1 * rstd * ga.y + be.y);
        *(float2*)&out[(size_t)row * D + lane * 2] = o;
    }
}

extern "C" void kernel_launch(void* const* d_in, const int* in_sizes, int n_in,
                              void* d_out, int out_size, void* d_ws, size_t ws_size,
                              hipStream_t stream) {
    // inputs: t, h, edge_index, batch_size, W, b, gamma, beta
    const float* h     = (const float*)d_in[1];
    const int*   ei    = (const int*)  d_in[2];
    const float* Wg    = (const float*)d_in[4];
    const float* b     = (const float*)d_in[5];
    const float* gamma = (const float*)d_in[6];
    const float* beta  = (const float*)d_in[7];
    float* out = (float*)d_out;

    // workspace layout
    int*            deg    = (int*)d_ws;                      // NN ints
    unsigned short* rank   = (unsigned short*)(deg + NN);     // NE ushorts
    int*            rowoff = (int*)(rank + NE);               // NN+1 ints
    float*          dinv   = (float*)(rowoff + NN + 1);       // NN floats
    int*            partial= (int*)(dinv + NN);               // 64 ints
    int*            csr    = partial + 64;                    // NE ints
    unsigned*       hb     = (unsigned*)(csr + NE);           // NN*64 uints (12.8MB)

    int tailN = out_size - NN * D;                 // int-zeros tail of d_out
    int* outtail = (int*)(out + (size_t)NN * D);

    hipMemsetAsync(deg, 0, NN * sizeof(int), stream);
    k_pre   <<<12500, 256, 0, stream>>>(h, hb, ei, deg, rank, outtail, tailN);
    k_scan_a<<<NSCAN, 256, 0, stream>>>(deg, partial, dinv);
    k_scan_c<<<NSCAN, 256, 0, stream>>>(deg, partial, rowoff);
    k_fill  <<<625,   320, 0, stream>>>(ei, rowoff, rank, csr);
    k_main  <<<NN / 16, 256, 0, stream>>>(rowoff, csr, dinv, h, hb, Wg, b, gamma, beta, out);
}

// Round 11
// 209.610 us; speedup vs baseline: 1.7556x; 1.2332x over previous
//
#include <hip/hip_runtime.h>
#include <math.h>

#define NN 50000
#define NE 800000
#define D  128
#define SCAN_CHUNK 1024
#define NSCAN ((NN + SCAN_CHUNK - 1) / SCAN_CHUNK)   // 49

typedef __attribute__((ext_vector_type(8))) short bf16x8;
typedef __attribute__((ext_vector_type(4))) float f32x4;

__device__ __forceinline__ unsigned short f32_to_bf16(float f) {
    unsigned u = __float_as_uint(f);
    u = u + 0x7FFFu + ((u >> 16) & 1u);   // RNE
    return (unsigned short)(u >> 16);
}

// ---- fused prep: h->bf16 + W->bf16 B-frag pack + deg/rank atomics + tail ----
__global__ __launch_bounds__(256) void k_pre(const float* __restrict__ h,
                                             unsigned* __restrict__ hb,
                                             const float* __restrict__ Wg,
                                             unsigned short* __restrict__ Wb,
                                             const int* __restrict__ ei,
                                             int* __restrict__ deg,
                                             unsigned short* __restrict__ rank,
                                             int* __restrict__ outtail, int tailN) {
    int t = blockIdx.x * 256 + threadIdx.x;   // grid 12500 -> NN*64 cvt items
    float2 v = ((const float2*)h)[t];
    unsigned a = __float_as_uint(v.x);
    unsigned b = __float_as_uint(v.y);
    a = a + 0x7FFFu + ((a >> 16) & 1u);
    b = b + 0x7FFFu + ((b >> 16) & 1u);
    hb[t] = (a >> 16) | (b & 0xFFFF0000u);    // plain bf16 array in dim order
    if (t < NE) {
        int dst = ei[NE + t];
        rank[t] = (unsigned short)atomicAdd(&deg[dst], 1);
    }
    if (t < D * D) {   // W[k][n] -> B-fragment layout (bf16)
        int k = t >> 7, n = t & 127;
        int frag = (n >> 4) * 256 + (k >> 5) * 64 + ((k >> 3) & 3) * 16 + (n & 15);
        Wb[frag * 8 + (k & 7)] = f32_to_bf16(Wg[t]);
    }
    if (t < tailN) outtail[t] = 0;
}

// ---- z = h @ W via MFMA 16x16x32 bf16; zb written IN PLACE over hb --------
// Block 256 = 4 waves, wave owns 16 rows (64 rows/block, grid 782).
// A: lane(quad,lo) holds A[m=rowBase+lo][k=kt*32+quad*8+j]  (uint4 from hb)
// B: lane(quad,lo) holds B[k=kt*32+quad*8+j][n=nt*16+lo]    (uint4 from Wb)
// C/D: col=lane&15, row=quad*4+reg (verified m89 mapping).
// In-place safe: stores depend on all 4 A-frag loads (via mfma chain), and
// each row is read+written by exactly one wave.
__global__ __launch_bounds__(256) void k_gemmz(const unsigned* __restrict__ hb,
                                               const unsigned short* __restrict__ Wb,
                                               unsigned short* __restrict__ zb) {
    int tid = threadIdx.x;
    int w = tid >> 6, lane = tid & 63;
    int quad = lane >> 4, lo = lane & 15;
    int rowBase = blockIdx.x * 64 + w * 16;
    int rowA = rowBase + lo; if (rowA > NN - 1) rowA = NN - 1;
    const uint4* hb4 = (const uint4*)hb;   // 16 uint4 per row (128 bf16)
    const uint4* Wb4 = (const uint4*)Wb;   // one uint4 per fragment slot

    bf16x8 af[4];
#pragma unroll
    for (int kt = 0; kt < 4; kt++) {
        uint4 ta = hb4[(size_t)rowA * 16 + kt * 4 + quad];
        af[kt] = __builtin_bit_cast(bf16x8, ta);
    }

    f32x4 acc[8];
#pragma unroll
    for (int nt = 0; nt < 8; nt++) acc[nt] = (f32x4){0.f, 0.f, 0.f, 0.f};

#pragma unroll
    for (int kt = 0; kt < 4; kt++) {
#pragma unroll
        for (int nt = 0; nt < 8; nt++) {
            uint4 tb = Wb4[nt * 256 + kt * 64 + lane];
            bf16x8 bfv = __builtin_bit_cast(bf16x8, tb);
            acc[nt] = __builtin_amdgcn_mfma_f32_16x16x32_bf16(af[kt], bfv, acc[nt], 0, 0, 0);
        }
    }

#pragma unroll
    for (int reg = 0; reg < 4; reg++) {
        int row = rowBase + quad * 4 + reg;
        if (row < NN) {
#pragma unroll
            for (int nt = 0; nt < 8; nt++)
                zb[(size_t)row * D + nt * 16 + lo] = f32_to_bf16(acc[nt][reg]);
        }
    }
}

// ---- fused scan: 49 blocks + device-atomic spin barrier (co-resident) -----
__global__ __launch_bounds__(256) void k_scan(const int* __restrict__ deg,
                                              int* __restrict__ partial,
                                              int* __restrict__ flag,
                                              int* __restrict__ rowoff,
                                              float* __restrict__ dinv) {
    __shared__ int sbuf[256];
    int t = threadIdx.x;
    int bid = blockIdx.x;
    int base = bid * SCAN_CHUNK + t * 4;
    int d[4]; int s = 0;
#pragma unroll
    for (int j = 0; j < 4; j++) {
        int i = base + j;
        d[j] = 0;
        if (i < NN) {
            d[j] = deg[i];
            s += d[j];
            dinv[i] = rsqrtf((float)d[j] + 1.0f);   // +1 self loop
        }
    }
    sbuf[t] = s; __syncthreads();
    for (int off = 1; off < 256; off <<= 1) {
        int v = (t >= off) ? sbuf[t - off] : 0;
        __syncthreads();
        sbuf[t] += v;
        __syncthreads();
    }
    if (t == 0) {
        atomicExch(&partial[bid], sbuf[255]);   // block total, device-coherent
        __threadfence();
        atomicAdd(flag, 1);
        while (atomicAdd(flag, 0) < NSCAN) {}   // 49 blocks co-resident: safe
    }
    __syncthreads();

    int lane = t & 63;
    int pv = (lane < NSCAN && lane < bid) ? atomicAdd(&partial[lane], 0) : 0;
#pragma unroll
    for (int off = 32; off > 0; off >>= 1) pv += __shfl_xor(pv, off, 64);

    int ex = sbuf[t] - s + pv;
#pragma unroll
    for (int j = 0; j < 4; j++) {
        int i = base + j;
        if (i < NN) {
            rowoff[i] = ex;
            ex += d[j];
            if (i == NN - 1) rowoff[NN] = ex;   // sentinel = NE
        }
    }
}

// ---------------- CSR fill: NO atomics (uses precomputed rank) ----------------
__global__ __launch_bounds__(320) void k_fill(const int* __restrict__ ei,
                                              const int* __restrict__ rowoff,
                                              const unsigned short* __restrict__ rank,
                                              int* __restrict__ csr) {
    int t = blockIdx.x * 320 + threadIdx.x;   // 625 blocks * 320 * 4 = NE
    int4 s4 = ((const int4*)ei)[t];
    int4 d4 = ((const int4*)(ei + NE))[t];
    ushort4 r4 = ((const ushort4*)rank)[t];
    csr[rowoff[d4.x] + r4.x] = s4.x;
    csr[rowoff[d4.y] + r4.y] = s4.y;
    csr[rowoff[d4.z] + r4.z] = s4.z;
    csr[rowoff[d4.w] + r4.w] = s4.w;
}

// ---- gather(z bf16) + bias + LN + tanh: NO GEMM phase, NO W traffic -------
// 256 thr = 4 indep waves, 4 rows/wave, NO LDS. y = dn*(dn*z[row] + sum
// dinv[s]*z[s]) + b, then LN, tanh. Edge loop x8-unrolled (MLP).
__global__ __launch_bounds__(256) void k_gather_ln(
        const int* __restrict__ rowoff, const int* __restrict__ csr,
        const float* __restrict__ dinv, const unsigned* __restrict__ zbu,
        const float* __restrict__ bias, const float* __restrict__ gamma,
        const float* __restrict__ beta, float* __restrict__ out) {
    int tid = threadIdx.x;
    int w = tid >> 6, lane = tid & 63;
    int rowBase = blockIdx.x * 16 + w * 4;

    float2 x[4];
    for (int r = 0; r < 4; r++) {
        int row = rowBase + r;
        float dn = dinv[row];
        unsigned zr = zbu[(size_t)row * 64 + lane];   // self loop (bf16 z)
        float2 a;
        a.x = dn * __uint_as_float(zr << 16);
        a.y = dn * __uint_as_float(zr & 0xFFFF0000u);
        int start = rowoff[row], end = rowoff[row + 1];
        for (int c = start; c < end; c += 64) {
            int m = end - c; if (m > 64) m = 64;
            int s = 0; float wv = 0.f;
            if (lane < m) { s = csr[c + lane]; wv = dinv[s]; }
            int j = 0;
            for (; j + 7 < m; j += 8) {          // 8 loads in flight
                unsigned p[8]; float wj[8];
#pragma unroll
                for (int q = 0; q < 8; q++) {
                    int sq = __shfl(s, j + q, 64);
                    wj[q]  = __shfl(wv, j + q, 64);
                    p[q]   = zbu[(size_t)sq * 64 + lane];
                }
#pragma unroll
                for (int q = 0; q < 8; q++) {
                    a.x = fmaf(wj[q], __uint_as_float(p[q] << 16), a.x);
                    a.y = fmaf(wj[q], __uint_as_float(p[q] & 0xFFFF0000u), a.y);
                }
            }
            for (; j < m; j++) {
                int   sj = __shfl(s,  j, 64);
                float fj = __shfl(wv, j, 64);
                unsigned pj = zbu[(size_t)sj * 64 + lane];
                a.x = fmaf(fj, __uint_as_float(pj << 16), a.x);
                a.y = fmaf(fj, __uint_as_float(pj & 0xFFFF0000u), a.y);
            }
        }
        a.x *= dn; a.y *= dn;
        x[r] = a;
    }

    float2 bi = ((const float2*)bias)[lane];
    float2 ga = ((const float2*)gamma)[lane];
    float2 be = ((const float2*)beta)[lane];
#pragma unroll
    for (int r = 0; r < 4; r++) {
        int row = rowBase + r;
        float y0 = x[r].x + bi.x;
        float y1 = x[r].y + bi.y;
        float s = y0 + y1;
#pragma unroll
        for (int off = 32; off > 0; off >>= 1) s += __shfl_xor(s, off, 64);
        float m = s * (1.0f / 128.0f);
        float v0 = y0 - m, v1 = y1 - m;
        float vs = v0 * v0 + v1 * v1;
#pragma unroll
        for (int off = 32; off > 0; off >>= 1) vs += __shfl_xor(vs, off, 64);
        float rstd = rsqrtf(vs * (1.0f / 128.0f) + 1e-5f);
        float2 o;
        o.x = tanhf(v0 * rstd * ga.x + be.x);
        o.y = tanhf(v1 * rstd * ga.y + be.y);
        *(float2*)&out[(size_t)row * D + lane * 2] = o;
    }
}

extern "C" void kernel_launch(void* const* d_in, const int* in_sizes, int n_in,
                              void* d_out, int out_size, void* d_ws, size_t ws_size,
                              hipStream_t stream) {
    // inputs: t, h, edge_index, batch_size, W, b, gamma, beta
    const float* h     = (const float*)d_in[1];
    const int*   ei    = (const int*)  d_in[2];
    const float* Wg    = (const float*)d_in[4];
    const float* b     = (const float*)d_in[5];
    const float* gamma = (const float*)d_in[6];
    const float* beta  = (const float*)d_in[7];
    float* out = (float*)d_out;

    // workspace layout (~18.3 MB; 30 MB proven available in R1)
    int*            deg    = (int*)d_ws;                      // NN ints
    int*            flag   = deg + NN;                        // 1 int (memset w/ deg)
    int*            partial= flag + 1;                        // 64 ints
    unsigned short* rank   = (unsigned short*)(partial + 64); // NE ushorts
    int*            rowoff = (int*)(rank + NE);               // NN+1 ints
    float*          dinv   = (float*)(rowoff + NN + 1);       // NN floats
    int*            csr    = (int*)(dinv + NN);               // NE ints
    unsigned*       hb     = (unsigned*)(csr + NE);           // NN*64 uints (12.8MB)
    unsigned short* Wb     = (unsigned short*)(hb + (size_t)NN * 64); // 16384 ushorts
    // zb aliases hb (in-place GEMM output)

    int tailN = out_size - NN * D;                 // int-zeros tail of d_out
    int* outtail = (int*)(out + (size_t)NN * D);

    hipMemsetAsync(deg, 0, (NN + 1) * sizeof(int), stream);   // deg + flag
    k_pre      <<<12500, 256, 0, stream>>>(h, hb, Wg, Wb, ei, deg, rank, outtail, tailN);
    k_gemmz    <<<782,   256, 0, stream>>>(hb, Wb, (unsigned short*)hb);
    k_scan     <<<NSCAN, 256, 0, stream>>>(deg, partial, flag, rowoff, dinv);
    k_fill     <<<625,   320, 0, stream>>>(ei, rowoff, rank, csr);
    k_gather_ln<<<NN / 16, 256, 0, stream>>>(rowoff, csr, dinv, hb, b, gamma, beta, out);
}

// Round 12
// 203.618 us; speedup vs baseline: 1.8073x; 1.0294x over previous
//
#include <hip/hip_runtime.h>
#include <math.h>

#define NN 50000
#define NE 800000
#define D  128
#define SCAN_CHUNK 1024
#define NSCAN ((NN + SCAN_CHUNK - 1) / SCAN_CHUNK)   // 49
#define PG_BLOCKS 782                                 // ceil(NN/64)

typedef __attribute__((ext_vector_type(8))) short bf16x8;
typedef __attribute__((ext_vector_type(4))) float f32x4;

__device__ __forceinline__ unsigned short f32_to_bf16(float f) {
    unsigned u = __float_as_uint(f);
    u = u + 0x7FFFu + ((u >> 16) & 1u);   // RNE
    return (unsigned short)(u >> 16);
}

// ---- fused: W->LDS B-frag pack + edge rank atomics + tail zero + z=hW ------
// 782 blocks x 256. Wave owns 16 rows. A: h fp32 -> bf16 in registers.
// B-frag LDS layout: frag = nt*256 + kt*64 + quad*16 + lo, elem j=k&7.
// C/D: col=lane&15, row=quad*4+reg (verified m89 mapping).
__global__ __launch_bounds__(256) void k_prep_gemm(
        const float* __restrict__ h,  const float* __restrict__ Wg,
        const int* __restrict__ ei,   int* __restrict__ deg,
        unsigned short* __restrict__ rank,
        unsigned short* __restrict__ zb,
        int* __restrict__ outtail, int tailN) {
    __shared__ unsigned short Wl[D * D];   // 32 KB, frag layout
    int tid = threadIdx.x;

    // stage W into LDS as bf16 B-fragments (coalesced global read)
#pragma unroll 4
    for (int i = 0; i < 64; i++) {
        int e = i * 256 + tid;             // 0..16383, = k*128+n
        int k = e >> 7, n = e & 127;
        int frag = (n >> 4) * 256 + (k >> 5) * 64 + ((k >> 3) & 3) * 16 + (n & 15);
        Wl[frag * 8 + (k & 7)] = f32_to_bf16(Wg[e]);
    }

    // edge rank atomics (4 edges/thread) + out-tail zeroing, overlaps W pack
    int g = blockIdx.x * 256 + tid;        // 0..200191
    if (g < NE / 4) {
        int4 d4 = ((const int4*)(ei + NE))[g];
        ushort4 r;
        r.x = (unsigned short)atomicAdd(&deg[d4.x], 1);
        r.y = (unsigned short)atomicAdd(&deg[d4.y], 1);
        r.z = (unsigned short)atomicAdd(&deg[d4.z], 1);
        r.w = (unsigned short)atomicAdd(&deg[d4.w], 1);
        ((ushort4*)rank)[g] = r;
    }
    for (int i = g; i < tailN; i += PG_BLOCKS * 256) outtail[i] = 0;

    // A fragments: 16 rows/wave, fp32 h -> bf16 registers
    int w = tid >> 6, lane = tid & 63;
    int quad = lane >> 4, lo = lane & 15;
    int rowBase = blockIdx.x * 64 + w * 16;
    int rowA = rowBase + lo; if (rowA > NN - 1) rowA = NN - 1;
    const float4* h4 = (const float4*)h;   // 32 float4 per row

    bf16x8 af[4];
#pragma unroll
    for (int kt = 0; kt < 4; kt++) {
        float4 u = h4[(size_t)rowA * 32 + kt * 8 + quad * 2];
        float4 v = h4[(size_t)rowA * 32 + kt * 8 + quad * 2 + 1];
        bf16x8 a;
        a[0] = (short)f32_to_bf16(u.x); a[1] = (short)f32_to_bf16(u.y);
        a[2] = (short)f32_to_bf16(u.z); a[3] = (short)f32_to_bf16(u.w);
        a[4] = (short)f32_to_bf16(v.x); a[5] = (short)f32_to_bf16(v.y);
        a[6] = (short)f32_to_bf16(v.z); a[7] = (short)f32_to_bf16(v.w);
        af[kt] = a;
    }
    __syncthreads();   // W pack complete

    f32x4 acc[8];
#pragma unroll
    for (int nt = 0; nt < 8; nt++) acc[nt] = (f32x4){0.f, 0.f, 0.f, 0.f};

    const uint4* Wl4 = (const uint4*)Wl;   // one uint4 per fragment slot
#pragma unroll
    for (int kt = 0; kt < 4; kt++) {
#pragma unroll
        for (int nt = 0; nt < 8; nt++) {
            uint4 tb = Wl4[nt * 256 + kt * 64 + lane];   // ds_read_b128
            bf16x8 bfv = __builtin_bit_cast(bf16x8, tb);
            acc[nt] = __builtin_amdgcn_mfma_f32_16x16x32_bf16(af[kt], bfv, acc[nt], 0, 0, 0);
        }
    }

#pragma unroll
    for (int reg = 0; reg < 4; reg++) {
        int row = rowBase + quad * 4 + reg;
        if (row < NN) {
#pragma unroll
            for (int nt = 0; nt < 8; nt++)
                zb[(size_t)row * D + nt * 16 + lo] = f32_to_bf16(acc[nt][reg]);
        }
    }
}

// ---- fused scan: 49 blocks + device-atomic spin barrier (co-resident) -----
__global__ __launch_bounds__(256) void k_scan(const int* __restrict__ deg,
                                              int* __restrict__ partial,
                                              int* __restrict__ flag,
                                              int* __restrict__ rowoff,
                                              float* __restrict__ dinv) {
    __shared__ int sbuf[256];
    int t = threadIdx.x;
    int bid = blockIdx.x;
    int base = bid * SCAN_CHUNK + t * 4;
    int d[4]; int s = 0;
#pragma unroll
    for (int j = 0; j < 4; j++) {
        int i = base + j;
        d[j] = 0;
        if (i < NN) {
            d[j] = deg[i];
            s += d[j];
            dinv[i] = rsqrtf((float)d[j] + 1.0f);   // +1 self loop
        }
    }
    sbuf[t] = s; __syncthreads();
    for (int off = 1; off < 256; off <<= 1) {
        int v = (t >= off) ? sbuf[t - off] : 0;
        __syncthreads();
        sbuf[t] += v;
        __syncthreads();
    }
    if (t == 0) {
        atomicExch(&partial[bid], sbuf[255]);
        __threadfence();
        atomicAdd(flag, 1);
        while (atomicAdd(flag, 0) < NSCAN) {}   // 49 blocks co-resident: safe
    }
    __syncthreads();

    int lane = t & 63;
    int pv = (lane < NSCAN && lane < bid) ? atomicAdd(&partial[lane], 0) : 0;
#pragma unroll
    for (int off = 32; off > 0; off >>= 1) pv += __shfl_xor(pv, off, 64);

    int ex = sbuf[t] - s + pv;
#pragma unroll
    for (int j = 0; j < 4; j++) {
        int i = base + j;
        if (i < NN) {
            rowoff[i] = ex;
            ex += d[j];
            if (i == NN - 1) rowoff[NN] = ex;   // sentinel = NE
        }
    }
}

// ---------------- CSR fill: NO atomics (uses precomputed rank) ----------------
__global__ __launch_bounds__(320) void k_fill(const int* __restrict__ ei,
                                              const int* __restrict__ rowoff,
                                              const unsigned short* __restrict__ rank,
                                              int* __restrict__ csr) {
    int t = blockIdx.x * 320 + threadIdx.x;   // 625 blocks * 320 * 4 = NE
    int4 s4 = ((const int4*)ei)[t];
    int4 d4 = ((const int4*)(ei + NE))[t];
    ushort4 r4 = ((const ushort4*)rank)[t];
    csr[rowoff[d4.x] + r4.x] = s4.x;
    csr[rowoff[d4.y] + r4.y] = s4.y;
    csr[rowoff[d4.z] + r4.z] = s4.z;
    csr[rowoff[d4.w] + r4.w] = s4.w;
}

// ---- gather(z bf16) + bias + LN + tanh: the hot kernel (49us @ R11) -------
// 256 thr = 4 indep waves, 4 rows/wave, NO LDS. Edge loop x8-unrolled (MLP).
__global__ __launch_bounds__(256) void k_gather_ln(
        const int* __restrict__ rowoff, const int* __restrict__ csr,
        const float* __restrict__ dinv, const unsigned* __restrict__ zbu,
        const float* __restrict__ bias, const float* __restrict__ gamma,
        const float* __restrict__ beta, float* __restrict__ out) {
    int tid = threadIdx.x;
    int w = tid >> 6, lane = tid & 63;
    int rowBase = blockIdx.x * 16 + w * 4;

    float2 x[4];
    for (int r = 0; r < 4; r++) {
        int row = rowBase + r;
        float dn = dinv[row];
        unsigned zr = zbu[(size_t)row * 64 + lane];   // self loop (bf16 z)
        float2 a;
        a.x = dn * __uint_as_float(zr << 16);
        a.y = dn * __uint_as_float(zr & 0xFFFF0000u);
        int start = rowoff[row], end = rowoff[row + 1];
        for (int c = start; c < end; c += 64) {
            int m = end - c; if (m > 64) m = 64;
            int s = 0; float wv = 0.f;
            if (lane < m) { s = csr[c + lane]; wv = dinv[s]; }
            int j = 0;
            for (; j + 7 < m; j += 8) {          // 8 loads in flight
                unsigned p[8]; float wj[8];
#pragma unroll
                for (int q = 0; q < 8; q++) {
                    int sq = __shfl(s, j + q, 64);
                    wj[q]  = __shfl(wv, j + q, 64);
                    p[q]   = zbu[(size_t)sq * 64 + lane];
                }
#pragma unroll
                for (int q = 0; q < 8; q++) {
                    a.x = fmaf(wj[q], __uint_as_float(p[q] << 16), a.x);
                    a.y = fmaf(wj[q], __uint_as_float(p[q] & 0xFFFF0000u), a.y);
                }
            }
            for (; j < m; j++) {
                int   sj = __shfl(s,  j, 64);
                float fj = __shfl(wv, j, 64);
                unsigned pj = zbu[(size_t)sj * 64 + lane];
                a.x = fmaf(fj, __uint_as_float(pj << 16), a.x);
                a.y = fmaf(fj, __uint_as_float(pj & 0xFFFF0000u), a.y);
            }
        }
        a.x *= dn; a.y *= dn;
        x[r] = a;
    }

    float2 bi = ((const float2*)bias)[lane];
    float2 ga = ((const float2*)gamma)[lane];
    float2 be = ((const float2*)beta)[lane];
#pragma unroll
    for (int r = 0; r < 4; r++) {
        int row = rowBase + r;
        float y0 = x[r].x + bi.x;
        float y1 = x[r].y + bi.y;
        float s = y0 + y1;
#pragma unroll
        for (int off = 32; off > 0; off >>= 1) s += __shfl_xor(s, off, 64);
        float m = s * (1.0f / 128.0f);
        float v0 = y0 - m, v1 = y1 - m;
        float vs = v0 * v0 + v1 * v1;
#pragma unroll
        for (int off = 32; off > 0; off >>= 1) vs += __shfl_xor(vs, off, 64);
        float rstd = rsqrtf(vs * (1.0f / 128.0f) + 1e-5f);
        float2 o;
        o.x = tanhf(v0 * rstd * ga.x + be.x);
        o.y = tanhf(v1 * rstd * ga.y + be.y);
        *(float2*)&out[(size_t)row * D + lane * 2] = o;
    }
}

extern "C" void kernel_launch(void* const* d_in, const int* in_sizes, int n_in,
                              void* d_out, int out_size, void* d_ws, size_t ws_size,
                              hipStream_t stream) {
    // inputs: t, h, edge_index, batch_size, W, b, gamma, beta
    const float* h     = (const float*)d_in[1];
    const int*   ei    = (const int*)  d_in[2];
    const float* Wg    = (const float*)d_in[4];
    const float* b     = (const float*)d_in[5];
    const float* gamma = (const float*)d_in[6];
    const float* beta  = (const float*)d_in[7];
    float* out = (float*)d_out;

    // workspace layout (~18.2 MB)
    int*            deg    = (int*)d_ws;                      // NN ints
    int*            flag   = deg + NN;                        // 1 int
    int*            partial= flag + 1;                        // 64 ints
    unsigned short* rank   = (unsigned short*)(partial + 64); // NE ushorts
    int*            rowoff = (int*)(rank + NE);               // NN+1 ints
    float*          dinv   = (float*)(rowoff + NN + 1);       // NN floats
    int*            csr    = (int*)(dinv + NN);               // NE ints
    unsigned short* zb     = (unsigned short*)(csr + NE);     // NN*128 ushorts (12.8MB)

    int tailN = out_size - NN * D;                 // int-zeros tail of d_out
    int* outtail = (int*)(out + (size_t)NN * D);

    hipMemsetAsync(deg, 0, (NN + 1) * sizeof(int), stream);   // deg + flag
    k_prep_gemm<<<PG_BLOCKS, 256, 0, stream>>>(h, Wg, ei, deg, rank, zb, outtail, tailN);
    k_scan     <<<NSCAN,     256, 0, stream>>>(deg, partial, flag, rowoff, dinv);
    k_fill     <<<625,       320, 0, stream>>>(ei, rowoff, rank, csr);
    k_gather_ln<<<NN / 16,   256, 0, stream>>>(rowoff, csr, dinv, (const unsigned*)zb, b, gamma, beta, out);
}